// Round 1
// baseline (615.812 us; speedup 1.0000x reference)
//
#include <hip/hip_runtime.h>
#include <hip/hip_bf16.h>

// out[n, :] = sum_{l=0..7} weight[l, x[n,l], :]
// N=131072, L=8, K=1024, D=1024, f32 in/out.
// One 256-thread block per row n; thread t owns float4 at column 4t.

#define N_ROWS 131072
#define L_DIM 8
#define K_DIM 1024
#define D_DIM 1024

__global__ __launch_bounds__(256) void speaker_gather_sum(
    const int* __restrict__ x,
    const float* __restrict__ w,
    float* __restrict__ out)
{
    const int n = blockIdx.x;
    const int t = threadIdx.x;              // 0..255, owns columns [4t, 4t+4)

    const int* __restrict__ xr = x + (size_t)n * L_DIM;

    float4 acc;
    acc.x = 0.f; acc.y = 0.f; acc.z = 0.f; acc.w = 0.f;

    #pragma unroll
    for (int l = 0; l < L_DIM; ++l) {
        const int k = xr[l];                // wave-uniform address -> scalar load
        const float* __restrict__ row =
            w + ((size_t)l * K_DIM + (size_t)k) * D_DIM + (size_t)t * 4;
        const float4 v = *reinterpret_cast<const float4*>(row);
        acc.x += v.x; acc.y += v.y; acc.z += v.z; acc.w += v.w;
    }

    *reinterpret_cast<float4*>(out + (size_t)n * D_DIM + (size_t)t * 4) = acc;
}

extern "C" void kernel_launch(void* const* d_in, const int* in_sizes, int n_in,
                              void* d_out, int out_size, void* d_ws, size_t ws_size,
                              hipStream_t stream)
{
    const int*   x = (const int*)d_in[0];     // (N, L) int32
    const float* w = (const float*)d_in[1];   // (L, K, D) f32
    float* out = (float*)d_out;               // (N, D) f32

    dim3 grid(N_ROWS);
    dim3 block(256);
    speaker_gather_sum<<<grid, block, 0, stream>>>(x, w, out);
}

// Round 3
// 335.559 us; speedup vs baseline: 1.8352x; 1.8352x over previous
//
#include <hip/hip_runtime.h>

// out[n, :] = sum_{l=0..7} weight[l, x[n,l], :]
// N=131072, L=8, K=1024, D=1024, f32 in/out.
//
// XCD-sliced layout: D is split into 8 slices of 128 columns. Block b handles
// slice (b%8); dispatch round-robins blocks across the 8 XCDs, so XCD j only
// ever touches weight columns [128j, 128j+128) -> a 4 MB working set that
// exactly fits its private L2. Gathered reads become L2 hits; output stores
// are non-temporal so the 512 MB write stream doesn't evict the slice.

#define N_ROWS 131072
#define L_DIM 8
#define K_DIM 1024
#define D_DIM 1024

#define NXCD 8
#define SLICE_COLS 128              // L*K*128*4B = 4 MB weight slice per XCD
#define ROWS_PER_BLOCK 128
#define CHUNKS (N_ROWS / ROWS_PER_BLOCK)   // 1024

typedef float f32x4 __attribute__((ext_vector_type(4)));

__global__ __launch_bounds__(256) void speaker_gather_sum_sliced(
    const int* __restrict__ x,
    const float* __restrict__ w,
    float* __restrict__ out)
{
    const int slice = blockIdx.x & (NXCD - 1);   // -> XCD id (round-robin dispatch)
    const int chunk = blockIdx.x >> 3;
    const int t    = threadIdx.x;
    const int rg   = t >> 5;                     // row-in-group, 0..7
    const int lane = t & 31;                     // column lane within slice

    const int col = slice * SLICE_COLS + lane * 4;
    const float* __restrict__ wbase = w + col;

    const int n0 = chunk * ROWS_PER_BLOCK;

    for (int r = rg; r < ROWS_PER_BLOCK; r += 8) {
        const int n = n0 + r;
        const int* __restrict__ xr = x + (size_t)n * L_DIM;

        f32x4 acc = (f32x4)(0.f);
        #pragma unroll
        for (int l = 0; l < L_DIM; ++l) {
            const int k = __builtin_nontemporal_load(xr + l);  // keep x out of L2
            const f32x4 v = *reinterpret_cast<const f32x4*>(
                wbase + (size_t)(l * K_DIM + k) * D_DIM);
            acc += v;
        }

        __builtin_nontemporal_store(acc,
            reinterpret_cast<f32x4*>(out + (size_t)n * D_DIM + col));
    }
}

extern "C" void kernel_launch(void* const* d_in, const int* in_sizes, int n_in,
                              void* d_out, int out_size, void* d_ws, size_t ws_size,
                              hipStream_t stream)
{
    const int*   x = (const int*)d_in[0];     // (N, L) int32
    const float* w = (const float*)d_in[1];   // (L, K, D) f32
    float* out = (float*)d_out;               // (N, D) f32

    dim3 grid(CHUNKS * NXCD);                 // 8192 blocks
    dim3 block(256);
    speaker_gather_sum_sliced<<<grid, block, 0, stream>>>(x, w, out);
}

// Round 4
// 204.764 us; speedup vs baseline: 3.0074x; 1.6388x over previous
//
#include <hip/hip_runtime.h>

// out[n, :] = sum_{l=0..7} weight[l, x[n,l], :]
// N=131072, L=8, K=1024, D=1024, f32 in/out.
//
// XCD-sliced: D split into 8 slices of 128 cols; block b handles slice b%8 so
// each XCD's private L2 holds exactly its 4 MB weight slice. This round:
// x staged in LDS (kills the idx->gather dependent latency chain + halves
// VMEM instrs), and 2 rows / 16 gathers in flight per iteration for MLP.

#define N_ROWS 131072
#define L_DIM 8
#define K_DIM 1024
#define D_DIM 1024

#define NXCD 8
#define SLICE_COLS 128              // L*K*128*4B = 4 MB weight slice per XCD
#define ROWS_PER_BLOCK 128
#define CHUNKS (N_ROWS / ROWS_PER_BLOCK)   // 1024

typedef float f32x4 __attribute__((ext_vector_type(4)));

__global__ __launch_bounds__(256) void speaker_gather_sum_sliced2(
    const int* __restrict__ x,
    const float* __restrict__ w,
    float* __restrict__ out)
{
    __shared__ int sx[ROWS_PER_BLOCK * L_DIM];   // 4 KB of indices

    const int slice = blockIdx.x & (NXCD - 1);   // -> XCD id (round-robin dispatch)
    const int chunk = blockIdx.x >> 3;
    const int t     = threadIdx.x;
    const int n0    = chunk * ROWS_PER_BLOCK;

    // Stage this block's x rows: 1024 ints = 256 int4, one coalesced load each.
    {
        const int4* __restrict__ src =
            reinterpret_cast<const int4*>(x + (size_t)n0 * L_DIM);
        reinterpret_cast<int4*>(sx)[t] = src[t];
    }
    __syncthreads();

    const int rg   = t >> 5;                     // row-group 0..7
    const int lane = t & 31;                     // column lane within slice
    const int col  = slice * SLICE_COLS + lane * 4;
    const float* __restrict__ wbase = w + col;

    #pragma unroll
    for (int i = 0; i < 8; ++i) {
        const int rA = rg + 16 * i;              // two rows per iteration
        const int rB = rA + 8;
        const int* __restrict__ xA = sx + rA * L_DIM;
        const int* __restrict__ xB = sx + rB * L_DIM;

        // Issue all 16 gathers before consuming any (compile-time indices).
        f32x4 vA[L_DIM], vB[L_DIM];
        #pragma unroll
        for (int l = 0; l < L_DIM; ++l)
            vA[l] = *reinterpret_cast<const f32x4*>(
                wbase + (size_t)(l * K_DIM + xA[l]) * D_DIM);
        #pragma unroll
        for (int l = 0; l < L_DIM; ++l)
            vB[l] = *reinterpret_cast<const f32x4*>(
                wbase + (size_t)(l * K_DIM + xB[l]) * D_DIM);

        f32x4 accA = ((vA[0] + vA[1]) + (vA[2] + vA[3]))
                   + ((vA[4] + vA[5]) + (vA[6] + vA[7]));
        f32x4 accB = ((vB[0] + vB[1]) + (vB[2] + vB[3]))
                   + ((vB[4] + vB[5]) + (vB[6] + vB[7]));

        __builtin_nontemporal_store(accA,
            reinterpret_cast<f32x4*>(out + (size_t)(n0 + rA) * D_DIM + col));
        __builtin_nontemporal_store(accB,
            reinterpret_cast<f32x4*>(out + (size_t)(n0 + rB) * D_DIM + col));
    }
}

extern "C" void kernel_launch(void* const* d_in, const int* in_sizes, int n_in,
                              void* d_out, int out_size, void* d_ws, size_t ws_size,
                              hipStream_t stream)
{
    const int*   x = (const int*)d_in[0];     // (N, L) int32
    const float* w = (const float*)d_in[1];   // (L, K, D) f32
    float* out = (float*)d_out;               // (N, D) f32

    dim3 grid(CHUNKS * NXCD);                 // 8192 blocks
    dim3 block(256);
    speaker_gather_sum_sliced2<<<grid, block, 0, stream>>>(x, w, out);
}